// Round 3
// baseline (429.097 us; speedup 1.0000x reference)
//
#include <hip/hip_runtime.h>
#include <hip/hip_bf16.h>

typedef __bf16 bf16_t;
typedef bf16_t bf16x8 __attribute__((ext_vector_type(8)));
typedef float floatx4 __attribute__((ext_vector_type(4)));

// ---------------------------------------------------------------------------
// GEMM1: C[m,n] = sum_k A[m,k]*W[n,k].  A,W fp32; compute bf16 MFMA; C bf16.
// 128x128 tile, 256 thr = 4 waves (2x2 of 64x64), BK=32, K=256 fixed.
// ---------------------------------------------------------------------------
__global__ __launch_bounds__(256) void gemm_f32_bf16out(
    const float* __restrict__ A, int lda,
    const float* __restrict__ W,      // (N,256) fp32 row-major
    bf16_t* __restrict__ Cmat, int ldc)
{
  constexpr int K = 256;
  __shared__ __align__(16) bf16_t As[128][40];
  __shared__ __align__(16) bf16_t Bs[128][40];

  const int tid = threadIdx.x;
  const int wave = tid >> 6, lane = tid & 63, quad = lane >> 4, l16 = lane & 15;
  const int wm = (wave >> 1) * 64, wn = (wave & 1) * 64;
  const long m0 = (long)blockIdx.y * 128;
  const int  n0 = blockIdx.x * 128;
  const int srow = tid >> 1;           // 0..127
  const int scol = (tid & 1) * 16;     // 0 / 16

  floatx4 acc[4][4] = {};

  for (int k0 = 0; k0 < K; k0 += 32) {
    {
      const float* p = A + (m0 + srow) * (long)lda + k0 + scol;
      float4 f[4];
#pragma unroll
      for (int u = 0; u < 4; ++u) f[u] = ((const float4*)p)[u];
      bf16_t tmp[16];
      const float* ff = (const float*)f;
#pragma unroll
      for (int u = 0; u < 16; ++u) tmp[u] = (bf16_t)ff[u];
      *(uint4*)(&As[srow][scol])     = *(const uint4*)(&tmp[0]);
      *(uint4*)(&As[srow][scol + 8]) = *(const uint4*)(&tmp[8]);
    }
    {
      const float* p = W + (n0 + srow) * (long)K + k0 + scol;
      float4 f[4];
#pragma unroll
      for (int u = 0; u < 4; ++u) f[u] = ((const float4*)p)[u];
      bf16_t tmp[16];
      const float* ff = (const float*)f;
#pragma unroll
      for (int u = 0; u < 16; ++u) tmp[u] = (bf16_t)ff[u];
      *(uint4*)(&Bs[srow][scol])     = *(const uint4*)(&tmp[0]);
      *(uint4*)(&Bs[srow][scol + 8]) = *(const uint4*)(&tmp[8]);
    }
    __syncthreads();

    bf16x8 af[4], bw[4];
#pragma unroll
    for (int i = 0; i < 4; ++i) {
      af[i] = *(const bf16x8*)(&As[wm + i * 16 + l16][quad * 8]);
      bw[i] = *(const bf16x8*)(&Bs[wn + i * 16 + l16][quad * 8]);
    }
#pragma unroll
    for (int i = 0; i < 4; ++i)
#pragma unroll
      for (int j = 0; j < 4; ++j)
        acc[i][j] = __builtin_amdgcn_mfma_f32_16x16x32_bf16(af[i], bw[j], acc[i][j], 0, 0, 0);
    __syncthreads();
  }

  // C/D layout: col = l16, row = quad*4 + r
#pragma unroll
  for (int j = 0; j < 4; ++j) {
    int n = n0 + wn + j * 16 + l16;
#pragma unroll
    for (int i = 0; i < 4; ++i)
#pragma unroll
      for (int r = 0; r < 4; ++r) {
        long m = m0 + wm + i * 16 + quad * 4 + r;
        Cmat[m * (long)ldc + n] = (bf16_t)acc[i][j][r];
      }
  }
}

// ---------------------------------------------------------------------------
// GEMM3: C[m,n] = sum_k A[m,k]*W[n,k] + bias[n].  A bf16 (lda); W,bias,C fp32.
// ---------------------------------------------------------------------------
__global__ __launch_bounds__(256) void gemm_bf16_f32out(
    const bf16_t* __restrict__ A, int lda,
    const float* __restrict__ W,      // (N,256) fp32
    const float* __restrict__ bias,
    float* __restrict__ Cmat, int ldc)
{
  constexpr int K = 256;
  __shared__ __align__(16) bf16_t As[128][40];
  __shared__ __align__(16) bf16_t Bs[128][40];

  const int tid = threadIdx.x;
  const int wave = tid >> 6, lane = tid & 63, quad = lane >> 4, l16 = lane & 15;
  const int wm = (wave >> 1) * 64, wn = (wave & 1) * 64;
  const long m0 = (long)blockIdx.y * 128;
  const int  n0 = blockIdx.x * 128;
  const int srow = tid >> 1;
  const int scol = (tid & 1) * 16;

  floatx4 acc[4][4] = {};

  for (int k0 = 0; k0 < K; k0 += 32) {
    // A: bf16 source, direct 16B copies (two uint4 per thread)
    *(uint4*)(&As[srow][scol])     = *(const uint4*)(A + (m0 + srow) * (long)lda + k0 + scol);
    *(uint4*)(&As[srow][scol + 8]) = *(const uint4*)(A + (m0 + srow) * (long)lda + k0 + scol + 8);
    {
      const float* p = W + (n0 + srow) * (long)K + k0 + scol;
      float4 f[4];
#pragma unroll
      for (int u = 0; u < 4; ++u) f[u] = ((const float4*)p)[u];
      bf16_t tmp[16];
      const float* ff = (const float*)f;
#pragma unroll
      for (int u = 0; u < 16; ++u) tmp[u] = (bf16_t)ff[u];
      *(uint4*)(&Bs[srow][scol])     = *(const uint4*)(&tmp[0]);
      *(uint4*)(&Bs[srow][scol + 8]) = *(const uint4*)(&tmp[8]);
    }
    __syncthreads();

    bf16x8 af[4], bw[4];
#pragma unroll
    for (int i = 0; i < 4; ++i) {
      af[i] = *(const bf16x8*)(&As[wm + i * 16 + l16][quad * 8]);
      bw[i] = *(const bf16x8*)(&Bs[wn + i * 16 + l16][quad * 8]);
    }
#pragma unroll
    for (int i = 0; i < 4; ++i)
#pragma unroll
      for (int j = 0; j < 4; ++j)
        acc[i][j] = __builtin_amdgcn_mfma_f32_16x16x32_bf16(af[i], bw[j], acc[i][j], 0, 0, 0);
    __syncthreads();
  }

#pragma unroll
  for (int j = 0; j < 4; ++j) {
    int n = n0 + wn + j * 16 + l16;
    float bv = bias[n];
#pragma unroll
    for (int i = 0; i < 4; ++i)
#pragma unroll
      for (int r = 0; r < 4; ++r) {
        long m = m0 + wm + i * 16 + quad * 4 + r;
        Cmat[m * (long)ldc + n] = acc[i][j][r] + bv;
      }
  }
}

// ---------------------------------------------------------------------------
// Attention (per reference): for each token s, S[h][e] = scale * q_h . k_e
// (8x8 over heads, dot over hd=32), softmax over e, out[h][:] = sum_e P*v_e.
// One block per window (49 tokens). K,V staged in LDS; q read from global.
// Output (head-major window scramble flat = h*1568+s*32+d) overwrites the
// V region of qkv — V is fully in LDS before any write. LDS total ~62.9KB.
// ---------------------------------------------------------------------------
__global__ __launch_bounds__(256) void attn_kernel(bf16_t* __restrict__ qkv)
{
  __shared__ __align__(16) bf16_t Kl[49][256];
  __shared__ __align__(16) bf16_t Vl[49][256];
  __shared__ float P[49][64];
  __shared__ int trow[49];

  const int n = blockIdx.x, tid = threadIdx.x;
  const int b = n >> 6, wh = (n >> 3) & 7, ww = n & 7;

  if (tid < 49) {
    int i = tid / 7, j = tid % 7;
    trow[tid] = b * 3136 + (wh * 7 + i) * 56 + ww * 7 + j;
  }
  __syncthreads();  // trow ready

  // stage K and V rows (49 x 256 bf16 each = 49*32 uint4 each)
  for (int idx = tid; idx < 49 * 32; idx += 256) {
    int s = idx >> 5, g = (idx & 31) * 8;
    *(uint4*)(&Kl[s][g]) = *(const uint4*)(qkv + (long)trow[s] * 768 + 256 + g);
    *(uint4*)(&Vl[s][g]) = *(const uint4*)(qkv + (long)trow[s] * 768 + 512 + g);
  }
  __syncthreads();

  const float scale = 0.17677669529663687f;  // 32^-0.5

  // per (s,h): 8 dots vs K rows (LDS), softmax over 8, write P row
  for (int idx = tid; idx < 49 * 8; idx += 256) {
    int s = idx >> 3, h = idx & 7;
    float qf[32];
    const bf16_t* qp = qkv + (long)trow[s] * 768 + h * 32;
#pragma unroll
    for (int u = 0; u < 4; ++u) {
      bf16x8 qv = *(const bf16x8*)(qp + u * 8);
#pragma unroll
      for (int d = 0; d < 8; ++d) qf[u * 8 + d] = (float)qv[d];
    }
    float v[8], mx = -INFINITY;
#pragma unroll
    for (int e = 0; e < 8; ++e) {
      float a = 0.f;
#pragma unroll
      for (int u = 0; u < 4; ++u) {
        bf16x8 kv = *(const bf16x8*)(&Kl[s][e * 32 + u * 8]);
#pragma unroll
        for (int d = 0; d < 8; ++d) a += qf[u * 8 + d] * (float)kv[d];
      }
      v[e] = a * scale;
      mx = fmaxf(mx, v[e]);
    }
    float sum = 0.f;
#pragma unroll
    for (int e = 0; e < 8; ++e) { v[e] = __expf(v[e] - mx); sum += v[e]; }
    float rs = 1.0f / sum;
#pragma unroll
    for (int e = 0; e < 8; ++e) P[s][h * 8 + e] = v[e] * rs;
  }
  __syncthreads();

  // out: entry (s2,c2) -> (h,s,d) via flat = s2*256+c2 = h*1568+s*32+d
  for (int idx = tid; idx < 49 * 256; idx += 256) {
    int s2 = idx >> 8, c2 = idx & 255;
    int flat = s2 * 256 + c2;
    int h = flat / 1568;
    int rem = flat - h * 1568;
    int s = rem >> 5, d = rem & 31;
    float a = 0.f;
#pragma unroll
    for (int e = 0; e < 8; ++e)
      a += P[s][h * 8 + e] * (float)Vl[s][e * 32 + d];
    qkv[(long)trow[s2] * 768 + 512 + c2] = (bf16_t)a;
  }
}

// ---------------------------------------------------------------------------
extern "C" void kernel_launch(void* const* d_in, const int* in_sizes, int n_in,
                              void* d_out, int out_size, void* d_ws, size_t ws_size,
                              hipStream_t stream) {
  (void)in_sizes; (void)n_in; (void)out_size;
  const float* x      = (const float*)d_in[0];
  const float* w_qkv  = (const float*)d_in[1];
  const float* w_proj = (const float*)d_in[2];
  const float* b_proj = (const float*)d_in[3];
  float* out = (float*)d_out;

  // Chunk over images so bf16 qkv scratch (rows x 768 x 2B) fits ws_size.
  const long rows_total = 100352;   // 32*56*56
  int nch = 16;                     // fallback: 9.6 MB
  for (int c = 1; c <= 16; c *= 2) {
    if ((size_t)(rows_total / c) * 768 * 2 <= ws_size) { nch = c; break; }
  }
  const long rows = rows_total / nch;   // divisible by 128 and by 49*64
  bf16_t* qkv = (bf16_t*)d_ws;

  for (int c = 0; c < nch; ++c) {
    const float* xc = x + c * rows * 256;
    float* outc = out + c * rows * 256;
    // 1) qkv = x @ w_qkv^T  (M=rows, N=768, K=256) -> bf16 scratch
    gemm_f32_bf16out<<<dim3(6, rows / 128), 256, 0, stream>>>(xc, 256, w_qkv, qkv, 768);
    // 2) per-token 8x8 head attention; writes scrambled pre-proj into V region
    attn_kernel<<<dim3((int)(rows / 49)), 256, 0, stream>>>(qkv);
    // 3) out = pre @ w_proj^T + b  (M=rows, N=256, K=256) -> fp32
    gemm_bf16_f32out<<<dim3(2, rows / 128), 256, 0, stream>>>(qkv + 512, 768, w_proj, b_proj, outc, 256);
  }
}

// Round 4
// 345.009 us; speedup vs baseline: 1.2437x; 1.2437x over previous
//
#include <hip/hip_runtime.h>
#include <hip/hip_bf16.h>

typedef __bf16 bf16_t;
typedef bf16_t bf16x8 __attribute__((ext_vector_type(8)));
typedef float floatx4 __attribute__((ext_vector_type(4)));

// ---------------------------------------------------------------------------
// One-time weight convert fp32 -> bf16 into workspace.
// wb layout: [0 .. 196607] = w_qkv (768x256), [196608 .. 262143] = w_proj.
// ---------------------------------------------------------------------------
__global__ __launch_bounds__(256) void wconv_kernel(
    const float* __restrict__ w_qkv, const float* __restrict__ w_proj,
    bf16_t* __restrict__ wb)
{
  int idx4 = (blockIdx.x * 256 + threadIdx.x) * 4;
  const float* src = (idx4 < 196608) ? (w_qkv + idx4) : (w_proj + (idx4 - 196608));
  float4 f = *(const float4*)src;
  bf16_t o[4] = {(bf16_t)f.x, (bf16_t)f.y, (bf16_t)f.z, (bf16_t)f.w};
  *(uint2*)(wb + idx4) = *(const uint2*)o;
}

// ---------------------------------------------------------------------------
// Fully fused window attention: one block per window (49 tokens), 256 thr.
// Phases: stage X -> K gemm -> (Q gemm + S/softmax) x4 head-pairs ->
//         V gemm (overwrites K region) -> PV (reg-buffered) -> scrambled pre
//         (in-place over V) -> proj gemm -> out.
// LDS ~63.7 KB -> 2 blocks/CU. All GEMMs 16x16x32 bf16 MFMA, M=49 padded 64.
// ---------------------------------------------------------------------------
__global__ __launch_bounds__(256, 2) void fused_kernel(
    const float* __restrict__ x,
    const bf16_t* __restrict__ wb,     // bf16 weights: qkv(768x256) then proj(256x256)
    const float* __restrict__ b_proj,
    float* __restrict__ out)
{
  __shared__ __align__(16) bf16_t Xs[49][264];   // 25.9 KB  x window (bf16)
  __shared__ __align__(16) bf16_t KV[49][264];   // 25.9 KB  K -> V -> pre
  __shared__ __align__(16) bf16_t Qt[49][72];    //  6.9 KB  per-pair Q tile
  __shared__ _Float16 Pl[49][64];                //  6.1 KB  softmax probs [s][h*8+e]
  __shared__ int trow[49];

  const int n = blockIdx.x;              // window id 0..2047
  const int b = n >> 6, wh = (n >> 3) & 7, ww = n & 7;
  const int tid = threadIdx.x;
  const int wave = tid >> 6, lane = tid & 63, quad = lane >> 4, l16 = lane & 15;
  const float scale = 0.17677669529663687f;  // 32^-0.5

  if (tid < 49) {
    int i = tid / 7, j = tid % 7;
    trow[tid] = b * 3136 + (wh * 7 + i) * 56 + ww * 7 + j;
  }
  __syncthreads();

  // ---- stage X: 49x256 fp32 -> bf16 LDS ----
  for (int idx = tid; idx < 49 * 32; idx += 256) {
    int s = idx >> 5, g = (idx & 31) * 8;
    const float* p = x + (long)trow[s] * 256 + g;
    float4 f0 = ((const float4*)p)[0];
    float4 f1 = ((const float4*)p)[1];
    bf16_t t8[8] = {(bf16_t)f0.x, (bf16_t)f0.y, (bf16_t)f0.z, (bf16_t)f0.w,
                    (bf16_t)f1.x, (bf16_t)f1.y, (bf16_t)f1.z, (bf16_t)f1.w};
    *(uint4*)(&Xs[s][g]) = *(const uint4*)t8;
  }
  __syncthreads();

  // ---- K gemm: K(49x256) = X @ Wk^T; waves split n by 64 -> KV ----
  {
    floatx4 acc[4][4] = {};
    const bf16_t* wk = wb + (256 + wave * 64) * 256;
    for (int k = 0; k < 8; ++k) {
      bf16x8 a[4], bfr[4];
#pragma unroll
      for (int i = 0; i < 4; ++i) {
        int mr = i * 16 + l16; if (mr > 48) mr = 48;
        a[i] = *(const bf16x8*)(&Xs[mr][k * 32 + quad * 8]);
      }
#pragma unroll
      for (int j = 0; j < 4; ++j)
        bfr[j] = *(const bf16x8*)(wk + (j * 16 + l16) * 256 + k * 32 + quad * 8);
#pragma unroll
      for (int i = 0; i < 4; ++i)
#pragma unroll
        for (int j = 0; j < 4; ++j)
          acc[i][j] = __builtin_amdgcn_mfma_f32_16x16x32_bf16(a[i], bfr[j], acc[i][j], 0, 0, 0);
    }
#pragma unroll
    for (int i = 0; i < 4; ++i)
#pragma unroll
      for (int r = 0; r < 4; ++r) {
        int m = i * 16 + quad * 4 + r;
        if (m < 49) {
#pragma unroll
          for (int j = 0; j < 4; ++j)
            KV[m][wave * 64 + j * 16 + l16] = (bf16_t)acc[i][j][r];
        }
      }
  }
  __syncthreads();

  // ---- Q gemm + S/softmax per head pair ----
  for (int hp = 0; hp < 4; ++hp) {
    floatx4 qacc[4] = {};
    const bf16_t* wq = wb + (hp * 64 + wave * 16) * 256;
    for (int k = 0; k < 8; ++k) {
      bf16x8 a[4];
#pragma unroll
      for (int i = 0; i < 4; ++i) {
        int mr = i * 16 + l16; if (mr > 48) mr = 48;
        a[i] = *(const bf16x8*)(&Xs[mr][k * 32 + quad * 8]);
      }
      bf16x8 bfr = *(const bf16x8*)(wq + l16 * 256 + k * 32 + quad * 8);
#pragma unroll
      for (int i = 0; i < 4; ++i)
        qacc[i] = __builtin_amdgcn_mfma_f32_16x16x32_bf16(a[i], bfr, qacc[i], 0, 0, 0);
    }
#pragma unroll
    for (int i = 0; i < 4; ++i)
#pragma unroll
      for (int r = 0; r < 4; ++r) {
        int m = i * 16 + quad * 4 + r;
        if (m < 49) Qt[m][wave * 16 + l16] = (bf16_t)qacc[i][r];
      }
    __syncthreads();

    if (tid < 98) {
      int s = tid >> 1, hl = tid & 1;
      float qf[32];
#pragma unroll
      for (int u = 0; u < 4; ++u) {
        bf16x8 qv = *(const bf16x8*)(&Qt[s][hl * 32 + u * 8]);
#pragma unroll
        for (int d = 0; d < 8; ++d) qf[u * 8 + d] = (float)qv[d];
      }
      float v[8], mx = -INFINITY;
#pragma unroll
      for (int e = 0; e < 8; ++e) {
        float a = 0.f;
#pragma unroll
        for (int u = 0; u < 4; ++u) {
          bf16x8 kv = *(const bf16x8*)(&KV[s][e * 32 + u * 8]);
#pragma unroll
          for (int d = 0; d < 8; ++d) a += qf[u * 8 + d] * (float)kv[d];
        }
        v[e] = a * scale;
        mx = fmaxf(mx, v[e]);
      }
      float sum = 0.f;
#pragma unroll
      for (int e = 0; e < 8; ++e) { v[e] = __expf(v[e] - mx); sum += v[e]; }
      float rs = 1.0f / sum;
      int h = hp * 2 + hl;
#pragma unroll
      for (int e = 0; e < 8; ++e) Pl[s][h * 8 + e] = (_Float16)(v[e] * rs);
    }
    __syncthreads();
  }

  // ---- V gemm: overwrite KV (K is dead after all S) ----
  {
    floatx4 acc[4][4] = {};
    const bf16_t* wv = wb + (512 + wave * 64) * 256;
    for (int k = 0; k < 8; ++k) {
      bf16x8 a[4], bfr[4];
#pragma unroll
      for (int i = 0; i < 4; ++i) {
        int mr = i * 16 + l16; if (mr > 48) mr = 48;
        a[i] = *(const bf16x8*)(&Xs[mr][k * 32 + quad * 8]);
      }
#pragma unroll
      for (int j = 0; j < 4; ++j)
        bfr[j] = *(const bf16x8*)(wv + (j * 16 + l16) * 256 + k * 32 + quad * 8);
#pragma unroll
      for (int i = 0; i < 4; ++i)
#pragma unroll
        for (int j = 0; j < 4; ++j)
          acc[i][j] = __builtin_amdgcn_mfma_f32_16x16x32_bf16(a[i], bfr[j], acc[i][j], 0, 0, 0);
    }
#pragma unroll
    for (int i = 0; i < 4; ++i)
#pragma unroll
      for (int r = 0; r < 4; ++r) {
        int m = i * 16 + quad * 4 + r;
        if (m < 49) {
#pragma unroll
          for (int j = 0; j < 4; ++j)
            KV[m][wave * 64 + j * 16 + l16] = (bf16_t)acc[i][j][r];
        }
      }
  }
  __syncthreads();

  // ---- PV: tasks (s,h), 392 total; outputs buffered in registers ----
  float o1[32], o2[32];
  {
    int s = tid >> 3, h = tid & 7;
    float p[8];
#pragma unroll
    for (int e = 0; e < 8; ++e) p[e] = (float)Pl[s][h * 8 + e];
#pragma unroll
    for (int d = 0; d < 32; ++d) o1[d] = 0.f;
#pragma unroll
    for (int e = 0; e < 8; ++e) {
      float pe = p[e];
#pragma unroll
      for (int u = 0; u < 4; ++u) {
        bf16x8 vv = *(const bf16x8*)(&KV[s][e * 32 + u * 8]);
#pragma unroll
        for (int d = 0; d < 8; ++d) o1[u * 8 + d] += pe * (float)vv[d];
      }
    }
  }
  if (tid < 136) {
    int t = tid + 256;
    int s = t >> 3, h = t & 7;
    float p[8];
#pragma unroll
    for (int e = 0; e < 8; ++e) p[e] = (float)Pl[s][h * 8 + e];
#pragma unroll
    for (int d = 0; d < 32; ++d) o2[d] = 0.f;
#pragma unroll
    for (int e = 0; e < 8; ++e) {
      float pe = p[e];
#pragma unroll
      for (int u = 0; u < 4; ++u) {
        bf16x8 vv = *(const bf16x8*)(&KV[s][e * 32 + u * 8]);
#pragma unroll
        for (int d = 0; d < 8; ++d) o2[u * 8 + d] += pe * (float)vv[d];
      }
    }
  }
  __syncthreads();  // all V reads done; now overwrite with scrambled pre

  {
    int s = tid >> 3, h = tid & 7;
    int flatb = h * 1568 + s * 32;          // never crosses a 256 boundary
    int s2 = flatb >> 8, c2 = flatb & 255;
#pragma unroll
    for (int u = 0; u < 4; ++u) {
      bf16_t t8[8];
#pragma unroll
      for (int d = 0; d < 8; ++d) t8[d] = (bf16_t)o1[u * 8 + d];
      *(uint4*)(&KV[s2][c2 + u * 8]) = *(const uint4*)t8;
    }
  }
  if (tid < 136) {
    int t = tid + 256;
    int s = t >> 3, h = t & 7;
    int flatb = h * 1568 + s * 32;
    int s2 = flatb >> 8, c2 = flatb & 255;
#pragma unroll
    for (int u = 0; u < 4; ++u) {
      bf16_t t8[8];
#pragma unroll
      for (int d = 0; d < 8; ++d) t8[d] = (bf16_t)o2[u * 8 + d];
      *(uint4*)(&KV[s2][c2 + u * 8]) = *(const uint4*)t8;
    }
  }
  __syncthreads();

  // ---- proj gemm: out(49x256) = pre @ Wp^T + bias ----
  {
    floatx4 acc[4][4] = {};
    const bf16_t* wp = wb + 196608 + (wave * 64) * 256;
    for (int k = 0; k < 8; ++k) {
      bf16x8 a[4], bfr[4];
#pragma unroll
      for (int i = 0; i < 4; ++i) {
        int mr = i * 16 + l16; if (mr > 48) mr = 48;
        a[i] = *(const bf16x8*)(&KV[mr][k * 32 + quad * 8]);
      }
#pragma unroll
      for (int j = 0; j < 4; ++j)
        bfr[j] = *(const bf16x8*)(wp + (j * 16 + l16) * 256 + k * 32 + quad * 8);
#pragma unroll
      for (int i = 0; i < 4; ++i)
#pragma unroll
        for (int j = 0; j < 4; ++j)
          acc[i][j] = __builtin_amdgcn_mfma_f32_16x16x32_bf16(a[i], bfr[j], acc[i][j], 0, 0, 0);
    }
#pragma unroll
    for (int j = 0; j < 4; ++j) {
      int col = wave * 64 + j * 16 + l16;
      float bv = b_proj[col];
#pragma unroll
      for (int i = 0; i < 4; ++i)
#pragma unroll
        for (int r = 0; r < 4; ++r) {
          int m = i * 16 + quad * 4 + r;
          if (m < 49) out[(long)trow[m] * 256 + col] = acc[i][j][r] + bv;
        }
    }
  }
}

// ---------------------------------------------------------------------------
extern "C" void kernel_launch(void* const* d_in, const int* in_sizes, int n_in,
                              void* d_out, int out_size, void* d_ws, size_t ws_size,
                              hipStream_t stream) {
  (void)in_sizes; (void)n_in; (void)out_size; (void)ws_size;
  const float* x      = (const float*)d_in[0];
  const float* w_qkv  = (const float*)d_in[1];
  const float* w_proj = (const float*)d_in[2];
  const float* b_proj = (const float*)d_in[3];
  float* out = (float*)d_out;
  bf16_t* wb = (bf16_t*)d_ws;   // 262144 bf16 = 512 KB

  wconv_kernel<<<dim3(256), 256, 0, stream>>>(w_qkv, w_proj, wb);
  fused_kernel<<<dim3(2048), 256, 0, stream>>>(x, wb, b_proj, out);
}

// Round 5
// 334.144 us; speedup vs baseline: 1.2842x; 1.0325x over previous
//
#include <hip/hip_runtime.h>
#include <hip/hip_bf16.h>

typedef __bf16 bf16_t;
typedef bf16_t bf16x8 __attribute__((ext_vector_type(8)));
typedef float floatx4 __attribute__((ext_vector_type(4)));

// ---------------------------------------------------------------------------
// One-time weight convert fp32 -> bf16 into workspace.
// wb layout: [0 .. 196607] = w_qkv (768x256), [196608 .. 262143] = w_proj.
// ---------------------------------------------------------------------------
__global__ __launch_bounds__(256) void wconv_kernel(
    const float* __restrict__ w_qkv, const float* __restrict__ w_proj,
    bf16_t* __restrict__ wb)
{
  int idx4 = (blockIdx.x * 256 + threadIdx.x) * 4;
  const float* src = (idx4 < 196608) ? (w_qkv + idx4) : (w_proj + (idx4 - 196608));
  float4 f = *(const float4*)src;
  bf16_t o[4] = {(bf16_t)f.x, (bf16_t)f.y, (bf16_t)f.z, (bf16_t)f.w};
  *(uint2*)(wb + idx4) = *(const uint2*)o;
}

// ---------------------------------------------------------------------------
// Fused window attention: one block per window (49 tokens), 512 thr = 8 waves.
// Same ~64KB LDS as round 4 but 2x the waves -> 16 waves/CU (50% occupancy).
// Phases: stage X -> K gemm (8 waves x 32 cols) -> 4x (Q gemm split over M and
// N + softmax) -> V gemm (overwrites K) -> PV (1 task/thread, reg-buffered)
// -> scrambled pre in-place -> proj gemm -> out.
// ---------------------------------------------------------------------------
__global__ __launch_bounds__(512, 4) void fused_kernel(
    const float* __restrict__ x,
    const bf16_t* __restrict__ wb,     // bf16 weights: qkv(768x256) then proj(256x256)
    const float* __restrict__ b_proj,
    float* __restrict__ out)
{
  __shared__ __align__(16) bf16_t Xs[49][264];   // 25.9 KB  x window (bf16)
  __shared__ __align__(16) bf16_t KV[49][264];   // 25.9 KB  K -> V -> pre
  __shared__ __align__(16) bf16_t Qt[49][72];    //  6.9 KB  per-pair Q tile
  __shared__ _Float16 Pl[49][64];                //  6.1 KB  probs [s][h*8+e]
  __shared__ int trow[49];

  const int n = blockIdx.x;              // window id 0..2047
  const int b = n >> 6, wh = (n >> 3) & 7, ww = n & 7;
  const int tid = threadIdx.x;
  const int wave = tid >> 6, lane = tid & 63, quad = lane >> 4, l16 = lane & 15;
  const float scale = 0.17677669529663687f;  // 32^-0.5

  if (tid < 49) {
    int i = tid / 7, j = tid % 7;
    trow[tid] = b * 3136 + (wh * 7 + i) * 56 + ww * 7 + j;
  }
  __syncthreads();

  // ---- stage X: 49x256 fp32 -> bf16 LDS ----
  for (int idx = tid; idx < 49 * 32; idx += 512) {
    int s = idx >> 5, g = (idx & 31) * 8;
    const float* p = x + (long)trow[s] * 256 + g;
    float4 f0 = ((const float4*)p)[0];
    float4 f1 = ((const float4*)p)[1];
    bf16_t t8[8] = {(bf16_t)f0.x, (bf16_t)f0.y, (bf16_t)f0.z, (bf16_t)f0.w,
                    (bf16_t)f1.x, (bf16_t)f1.y, (bf16_t)f1.z, (bf16_t)f1.w};
    *(uint4*)(&Xs[s][g]) = *(const uint4*)t8;
  }
  __syncthreads();

  // ---- K gemm: K(49x256) = X @ Wk^T; 8 waves x 32 cols -> KV ----
  {
    floatx4 acc[4][2] = {};
    const int cb = wave * 32;
    const bf16_t* wk = wb + (256 + cb) * 256;
#pragma unroll
    for (int k = 0; k < 8; ++k) {
      bf16x8 a[4], bfr[2];
#pragma unroll
      for (int i = 0; i < 4; ++i) {
        int mr = i * 16 + l16; if (mr > 48) mr = 48;
        a[i] = *(const bf16x8*)(&Xs[mr][k * 32 + quad * 8]);
      }
#pragma unroll
      for (int j = 0; j < 2; ++j)
        bfr[j] = *(const bf16x8*)(wk + (j * 16 + l16) * 256 + k * 32 + quad * 8);
#pragma unroll
      for (int i = 0; i < 4; ++i)
#pragma unroll
        for (int j = 0; j < 2; ++j)
          acc[i][j] = __builtin_amdgcn_mfma_f32_16x16x32_bf16(a[i], bfr[j], acc[i][j], 0, 0, 0);
    }
#pragma unroll
    for (int i = 0; i < 4; ++i)
#pragma unroll
      for (int r = 0; r < 4; ++r) {
        int m = i * 16 + quad * 4 + r;
        if (m < 49) {
#pragma unroll
          for (int j = 0; j < 2; ++j)
            KV[m][cb + j * 16 + l16] = (bf16_t)acc[i][j][r];
        }
      }
  }
  __syncthreads();

  // ---- Q gemm + S/softmax per head pair; Q split over M(2) x N(4) waves ----
  for (int hp = 0; hp < 4; ++hp) {
    const int jw = wave & 3;         // n-tile 0..3 (16 cols)
    const int ih = wave >> 2;        // m-half 0..1 (i in {2ih, 2ih+1})
    floatx4 qacc[2] = {};
    const bf16_t* wq = wb + (hp * 64 + jw * 16) * 256;
#pragma unroll
    for (int k = 0; k < 8; ++k) {
      bf16x8 a[2];
#pragma unroll
      for (int ii = 0; ii < 2; ++ii) {
        int mr = (ih * 2 + ii) * 16 + l16; if (mr > 48) mr = 48;
        a[ii] = *(const bf16x8*)(&Xs[mr][k * 32 + quad * 8]);
      }
      bf16x8 bfr = *(const bf16x8*)(wq + l16 * 256 + k * 32 + quad * 8);
#pragma unroll
      for (int ii = 0; ii < 2; ++ii)
        qacc[ii] = __builtin_amdgcn_mfma_f32_16x16x32_bf16(a[ii], bfr, qacc[ii], 0, 0, 0);
    }
#pragma unroll
    for (int ii = 0; ii < 2; ++ii)
#pragma unroll
      for (int r = 0; r < 4; ++r) {
        int m = (ih * 2 + ii) * 16 + quad * 4 + r;
        if (m < 49) Qt[m][jw * 16 + l16] = (bf16_t)qacc[ii][r];
      }
    __syncthreads();

    if (tid < 98) {
      int s = tid >> 1, hl = tid & 1;
      float qf[32];
#pragma unroll
      for (int u = 0; u < 4; ++u) {
        bf16x8 qv = *(const bf16x8*)(&Qt[s][hl * 32 + u * 8]);
#pragma unroll
        for (int d = 0; d < 8; ++d) qf[u * 8 + d] = (float)qv[d];
      }
      float v[8], mx = -INFINITY;
#pragma unroll
      for (int e = 0; e < 8; ++e) {
        float a = 0.f;
#pragma unroll
        for (int u = 0; u < 4; ++u) {
          bf16x8 kv = *(const bf16x8*)(&KV[s][e * 32 + u * 8]);
#pragma unroll
          for (int d = 0; d < 8; ++d) a += qf[u * 8 + d] * (float)kv[d];
        }
        v[e] = a * scale;
        mx = fmaxf(mx, v[e]);
      }
      float sum = 0.f;
#pragma unroll
      for (int e = 0; e < 8; ++e) { v[e] = __expf(v[e] - mx); sum += v[e]; }
      float rs = 1.0f / sum;
      int h = hp * 2 + hl;
#pragma unroll
      for (int e = 0; e < 8; ++e) Pl[s][h * 8 + e] = (_Float16)(v[e] * rs);
    }
    __syncthreads();
  }

  // ---- V gemm: overwrite KV (K dead after last softmax) ----
  {
    floatx4 acc[4][2] = {};
    const int cb = wave * 32;
    const bf16_t* wv = wb + (512 + cb) * 256;
#pragma unroll
    for (int k = 0; k < 8; ++k) {
      bf16x8 a[4], bfr[2];
#pragma unroll
      for (int i = 0; i < 4; ++i) {
        int mr = i * 16 + l16; if (mr > 48) mr = 48;
        a[i] = *(const bf16x8*)(&Xs[mr][k * 32 + quad * 8]);
      }
#pragma unroll
      for (int j = 0; j < 2; ++j)
        bfr[j] = *(const bf16x8*)(wv + (j * 16 + l16) * 256 + k * 32 + quad * 8);
#pragma unroll
      for (int i = 0; i < 4; ++i)
#pragma unroll
        for (int j = 0; j < 2; ++j)
          acc[i][j] = __builtin_amdgcn_mfma_f32_16x16x32_bf16(a[i], bfr[j], acc[i][j], 0, 0, 0);
    }
#pragma unroll
    for (int i = 0; i < 4; ++i)
#pragma unroll
      for (int r = 0; r < 4; ++r) {
        int m = i * 16 + quad * 4 + r;
        if (m < 49) {
#pragma unroll
          for (int j = 0; j < 2; ++j)
            KV[m][wave * 32 + j * 16 + l16] = (bf16_t)acc[i][j][r];
        }
      }
  }
  __syncthreads();

  // ---- PV: one task per thread (s,h), 392 total; reg-buffered ----
  float o1[32];
  if (tid < 392) {
    int s = tid >> 3, h = tid & 7;
    float p[8];
#pragma unroll
    for (int e = 0; e < 8; ++e) p[e] = (float)Pl[s][h * 8 + e];
#pragma unroll
    for (int d = 0; d < 32; ++d) o1[d] = 0.f;
#pragma unroll
    for (int e = 0; e < 8; ++e) {
      float pe = p[e];
#pragma unroll
      for (int u = 0; u < 4; ++u) {
        bf16x8 vv = *(const bf16x8*)(&KV[s][e * 32 + u * 8]);
#pragma unroll
        for (int d = 0; d < 8; ++d) o1[u * 8 + d] += pe * (float)vv[d];
      }
    }
  }
  __syncthreads();  // all V reads done; now overwrite with scrambled pre

  if (tid < 392) {
    int s = tid >> 3, h = tid & 7;
    int flatb = h * 1568 + s * 32;          // never crosses a 256 boundary
    int s2 = flatb >> 8, c2 = flatb & 255;
#pragma unroll
    for (int u = 0; u < 4; ++u) {
      bf16_t t8[8];
#pragma unroll
      for (int d = 0; d < 8; ++d) t8[d] = (bf16_t)o1[u * 8 + d];
      *(uint4*)(&KV[s2][c2 + u * 8]) = *(const uint4*)t8;
    }
  }
  __syncthreads();

  // ---- proj gemm: out(49x256) = pre @ Wp^T + bias; 8 waves x 32 cols ----
  {
    floatx4 acc[4][2] = {};
    const int cb = wave * 32;
    const bf16_t* wp = wb + 196608 + cb * 256;
#pragma unroll
    for (int k = 0; k < 8; ++k) {
      bf16x8 a[4], bfr[2];
#pragma unroll
      for (int i = 0; i < 4; ++i) {
        int mr = i * 16 + l16; if (mr > 48) mr = 48;
        a[i] = *(const bf16x8*)(&KV[mr][k * 32 + quad * 8]);
      }
#pragma unroll
      for (int j = 0; j < 2; ++j)
        bfr[j] = *(const bf16x8*)(wp + (j * 16 + l16) * 256 + k * 32 + quad * 8);
#pragma unroll
      for (int i = 0; i < 4; ++i)
#pragma unroll
        for (int j = 0; j < 2; ++j)
          acc[i][j] = __builtin_amdgcn_mfma_f32_16x16x32_bf16(a[i], bfr[j], acc[i][j], 0, 0, 0);
    }
#pragma unroll
    for (int j = 0; j < 2; ++j) {
      int col = cb + j * 16 + l16;
      float bv = b_proj[col];
#pragma unroll
      for (int i = 0; i < 4; ++i)
#pragma unroll
        for (int r = 0; r < 4; ++r) {
          int m = i * 16 + quad * 4 + r;
          if (m < 49) out[(long)trow[m] * 256 + col] = acc[i][j][r] + bv;
        }
    }
  }
}

// ---------------------------------------------------------------------------
extern "C" void kernel_launch(void* const* d_in, const int* in_sizes, int n_in,
                              void* d_out, int out_size, void* d_ws, size_t ws_size,
                              hipStream_t stream) {
  (void)in_sizes; (void)n_in; (void)out_size; (void)ws_size;
  const float* x      = (const float*)d_in[0];
  const float* w_qkv  = (const float*)d_in[1];
  const float* w_proj = (const float*)d_in[2];
  const float* b_proj = (const float*)d_in[3];
  float* out = (float*)d_out;
  bf16_t* wb = (bf16_t*)d_ws;   // 262144 bf16 = 512 KB

  wconv_kernel<<<dim3(256), 256, 0, stream>>>(w_qkv, w_proj, wb);
  fused_kernel<<<dim3(2048), 512, 0, stream>>>(x, wb, b_proj, out);
}